// Round 2
// baseline (431.030 us; speedup 1.0000x reference)
//
#include <hip/hip_runtime.h>

// Chain of 9 Linear layers, no activation => collapse to one affine map.
// dims: 784 -> 69 -> 31 -> 10 -> 10 -> ... -> 10
//
// Plan:
//   P1 (1 block):  S8 = W8*W7*...*W1  [10,69], d8 = collapsed bias of layers 1..8,
//                  beff = S8 @ b0 + d8  [10]
//   P2 (31 blocks): Wt[j*10+o] = sum_t S8[o][t] * W0[t][j]   (transposed for scalar loads)
//   MAIN (512 blocks x 128 thr): out[b][o] = sum_j x[b][j]*Wt[j*10+o] + beff[o]
//                  memory-bound: 205.5 MB read of x.

#define ROWS 128
#define CHUNK 56        // floats of K per chunk; 784 = 14*56
#define NV 14           // float4 per row per chunk
#define STRIDE 58       // padded LDS row stride in words (b64-aligned, odd/2 -> 4-way max)
#define NCHUNK 14

__global__ void prep_collapse(
    const float* __restrict__ W1, const float* __restrict__ b1,
    const float* __restrict__ W2, const float* __restrict__ b2,
    const float* __restrict__ W3, const float* __restrict__ b3,
    const float* __restrict__ W4, const float* __restrict__ b4,
    const float* __restrict__ W5, const float* __restrict__ b5,
    const float* __restrict__ W6, const float* __restrict__ b6,
    const float* __restrict__ W7, const float* __restrict__ b7,
    const float* __restrict__ W8, const float* __restrict__ b8,
    const float* __restrict__ b0,
    float* __restrict__ S8out, float* __restrict__ beff)
{
    __shared__ float Sa[31 * 69], Sb[31 * 69];
    __shared__ float da[31], db[31];
    const int t = threadIdx.x;
    const int nt = blockDim.x;

    // S = W1 [31,69], d = b1
    for (int i = t; i < 31 * 69; i += nt) Sa[i] = W1[i];
    for (int i = t; i < 31; i += nt) da[i] = b1[i];
    __syncthreads();

    // k=2: W2 [10,31] @ Sa -> Sb [10,69]
    for (int i = t; i < 10 * 69; i += nt) {
        int o = i / 69, c = i - o * 69;
        float s = 0.f;
        for (int k = 0; k < 31; k++) s += W2[o * 31 + k] * Sa[k * 69 + c];
        Sb[i] = s;
    }
    for (int i = t; i < 10; i += nt) {
        float s = b2[i];
        for (int k = 0; k < 31; k++) s += W2[i * 31 + k] * da[k];
        db[i] = s;
    }
    __syncthreads();

    // k=3..8: [10,10] @ [10,69], ping-pong Sb<->Sa.
    // NOTE: no arrays of LDS pointers (gfx950 rejects addrspace(3) static
    // initializers) — select buffers with runtime ternaries instead.
    const float* Wk[6] = { W3, W4, W5, W6, W7, W8 };
    const float* bk[6] = { b3, b4, b5, b6, b7, b8 };
    int src = 1;  // current data lives in Sb/db
    for (int st = 0; st < 6; st++) {
        const float* W = Wk[st];
        const float* bb = bk[st];
        float* S  = src ? Sb : Sa;
        float* D  = src ? Sa : Sb;
        float* dd = src ? db : da;
        float* dn = src ? da : db;
        for (int i = t; i < 10 * 69; i += nt) {
            int o = i / 69, c = i - o * 69;
            float s = 0.f;
            for (int k = 0; k < 10; k++) s += W[o * 10 + k] * S[k * 69 + c];
            D[i] = s;
        }
        for (int i = t; i < 10; i += nt) {
            float s = bb[i];
            for (int k = 0; k < 10; k++) s += W[i * 10 + k] * dd[k];
            dn[i] = s;
        }
        __syncthreads();
        src ^= 1;
    }

    // S8 lives in (src ? Sb : Sa); beff = S8 @ b0 + d8
    float* S  = src ? Sb : Sa;
    float* dd = src ? db : da;
    for (int i = t; i < 690; i += nt) S8out[i] = S[i];
    for (int i = t; i < 10; i += nt) {
        float s = dd[i];
        for (int k = 0; k < 69; k++) s += S[i * 69 + k] * b0[k];
        beff[i] = s;
    }
}

__global__ void prep_fold0(const float* __restrict__ W0,
                           const float* __restrict__ S8,
                           float* __restrict__ Wt)
{
    int idx = blockIdx.x * blockDim.x + threadIdx.x;  // o*784 + j
    if (idx >= 7840) return;
    int o = idx / 784, j = idx - o * 784;
    float s = 0.f;
    for (int k = 0; k < 69; k++) s += S8[o * 69 + k] * W0[k * 784 + j];
    Wt[j * 10 + o] = s;  // transposed: consecutive o for fixed j
}

__global__ __launch_bounds__(128) void linear_main(
    const float* __restrict__ x, const float* __restrict__ Wt,
    const float* __restrict__ beff, float* __restrict__ out)
{
    __shared__ float lds[2][ROWS * STRIDE];
    const int t = threadIdx.x;
    const long rowBase = (long)blockIdx.x * ROWS;
    const float* xbase = x + rowBase * 784;

    float acc[10];
#pragma unroll
    for (int o = 0; o < 10; o++) acc[o] = 0.f;

    float4 r[NV];

    // prologue: load chunk 0, deposit to buf 0
#pragma unroll
    for (int k = 0; k < NV; k++) {
        int f = t + k * 128;
        int row = f / NV, v = f - row * NV;
        r[k] = *(const float4*)(xbase + row * 784 + v * 4);
    }
#pragma unroll
    for (int k = 0; k < NV; k++) {
        int f = t + k * 128;
        int row = f / NV, v = f - row * NV;
        float* p = &lds[0][row * STRIDE + v * 4];
        ((float2*)p)[0] = make_float2(r[k].x, r[k].y);
        ((float2*)p)[1] = make_float2(r[k].z, r[k].w);
    }
    __syncthreads();

    for (int c = 0; c < NCHUNK; c++) {
        // prefetch next chunk into registers (overlaps compute below)
        if (c + 1 < NCHUNK) {
#pragma unroll
            for (int k = 0; k < NV; k++) {
                int f = t + k * 128;
                int row = f / NV, v = f - row * NV;
                r[k] = *(const float4*)(xbase + row * 784 + (c + 1) * CHUNK + v * 4);
            }
        }
        // compute: this thread's row lives at lds[c&1][t*STRIDE ..]
        const float* __restrict__ wp = Wt + c * CHUNK * 10;  // wave-uniform -> s_load
        const float* xp = &lds[c & 1][t * STRIDE];
#pragma unroll
        for (int j = 0; j < CHUNK; j++) {
            float xv = xp[j];
#pragma unroll
            for (int o = 0; o < 10; o++) acc[o] = fmaf(xv, wp[j * 10 + o], acc[o]);
        }
        __syncthreads();  // all waves done reading lds[c&1]
        if (c + 1 < NCHUNK) {
            float* dst = &lds[(c + 1) & 1][0];
#pragma unroll
            for (int k = 0; k < NV; k++) {
                int f = t + k * 128;
                int row = f / NV, v = f - row * NV;
                float* p = &dst[row * STRIDE + v * 4];
                ((float2*)p)[0] = make_float2(r[k].x, r[k].y);
                ((float2*)p)[1] = make_float2(r[k].z, r[k].w);
            }
            __syncthreads();  // writes visible before next compute
        }
    }

    // epilogue: bias + store (float2 stores; row*40B is 8-aligned)
    float* op = out + (rowBase + t) * 10;
#pragma unroll
    for (int o = 0; o < 10; o += 2) {
        *(float2*)(op + o) = make_float2(acc[o] + beff[o], acc[o + 1] + beff[o + 1]);
    }
}

extern "C" void kernel_launch(void* const* d_in, const int* in_sizes, int n_in,
                              void* d_out, int out_size, void* d_ws, size_t ws_size,
                              hipStream_t stream) {
    const float* x  = (const float*)d_in[0];
    const float* W0 = (const float*)d_in[1];
    const float* b0 = (const float*)d_in[2];
    const float* W1 = (const float*)d_in[3];
    const float* b1 = (const float*)d_in[4];
    const float* W2 = (const float*)d_in[5];
    const float* b2 = (const float*)d_in[6];
    const float* W3 = (const float*)d_in[7];
    const float* b3 = (const float*)d_in[8];
    const float* W4 = (const float*)d_in[9];
    const float* b4 = (const float*)d_in[10];
    const float* W5 = (const float*)d_in[11];
    const float* b5 = (const float*)d_in[12];
    const float* W6 = (const float*)d_in[13];
    const float* b6 = (const float*)d_in[14];
    const float* W7 = (const float*)d_in[15];
    const float* b7 = (const float*)d_in[16];
    const float* W8 = (const float*)d_in[17];
    const float* b8 = (const float*)d_in[18];

    float* ws   = (float*)d_ws;
    float* Wt   = ws;            // 7840 floats: [784][10]
    float* beff = ws + 7840;     // 10 floats
    float* S8   = ws + 7856;     // 690 floats

    float* out = (float*)d_out;
    const int B = in_sizes[0] / 784;  // 65536

    prep_collapse<<<1, 256, 0, stream>>>(W1, b1, W2, b2, W3, b3, W4, b4,
                                         W5, b5, W6, b6, W7, b7, W8, b8,
                                         b0, S8, beff);
    prep_fold0<<<31, 256, 0, stream>>>(W0, S8, Wt);
    linear_main<<<B / ROWS, 128, 0, stream>>>(x, Wt, beff, out);
}

// Round 3
// 370.101 us; speedup vs baseline: 1.1646x; 1.1646x over previous
//
#include <hip/hip_runtime.h>

// Chain of 9 Linear layers, no activation => collapse to one affine map.
// dims: 784 -> 69 -> 31 -> 10 -> ... -> 10
//
//   P1 (1 block):   S8 = W8*...*W1 [10,69], beff = S8 @ b0 + collapsed bias
//   P2 (31 blocks): Wt[j*10+o] = sum_k S8[o][k] * W0[k][j]   ([784][10], o fastest)
//   MAIN: out[b][o] = sum_j x[b][j]*Wt[j*10+o] + beff[o]
//
// MAIN design (R3): row-split-by-wave. Block = 256 thr = 4 waves, 64 rows.
//   Wave q covers j in [q*196,(q+1)*196): j is wave-uniform -> Wt via s_load.
//   Lane l = row. No LDS staging, no main-loop barriers; partials combined
//   through 7.7 KB LDS once at the end. 1024 blocks -> 16 waves/CU (vs 4 in
//   R2's thread-per-row, which capped occupancy at 1 wave/SIMD).

__global__ void prep_collapse(
    const float* __restrict__ W1, const float* __restrict__ b1,
    const float* __restrict__ W2, const float* __restrict__ b2,
    const float* __restrict__ W3, const float* __restrict__ b3,
    const float* __restrict__ W4, const float* __restrict__ b4,
    const float* __restrict__ W5, const float* __restrict__ b5,
    const float* __restrict__ W6, const float* __restrict__ b6,
    const float* __restrict__ W7, const float* __restrict__ b7,
    const float* __restrict__ W8, const float* __restrict__ b8,
    const float* __restrict__ b0,
    float* __restrict__ S8out, float* __restrict__ beff)
{
    __shared__ float Sa[31 * 69], Sb[31 * 69];
    __shared__ float da[31], db[31];
    const int t = threadIdx.x;
    const int nt = blockDim.x;

    for (int i = t; i < 31 * 69; i += nt) Sa[i] = W1[i];
    for (int i = t; i < 31; i += nt) da[i] = b1[i];
    __syncthreads();

    for (int i = t; i < 10 * 69; i += nt) {
        int o = i / 69, c = i - o * 69;
        float s = 0.f;
        for (int k = 0; k < 31; k++) s += W2[o * 31 + k] * Sa[k * 69 + c];
        Sb[i] = s;
    }
    for (int i = t; i < 10; i += nt) {
        float s = b2[i];
        for (int k = 0; k < 31; k++) s += W2[i * 31 + k] * da[k];
        db[i] = s;
    }
    __syncthreads();

    const float* Wk[6] = { W3, W4, W5, W6, W7, W8 };
    const float* bk[6] = { b3, b4, b5, b6, b7, b8 };
    int src = 1;  // runtime ternaries: gfx950 rejects arrays of LDS pointers
    for (int st = 0; st < 6; st++) {
        const float* W = Wk[st];
        const float* bb = bk[st];
        float* S  = src ? Sb : Sa;
        float* D  = src ? Sa : Sb;
        float* dd = src ? db : da;
        float* dn = src ? da : db;
        for (int i = t; i < 10 * 69; i += nt) {
            int o = i / 69, c = i - o * 69;
            float s = 0.f;
            for (int k = 0; k < 10; k++) s += W[o * 10 + k] * S[k * 69 + c];
            D[i] = s;
        }
        for (int i = t; i < 10; i += nt) {
            float s = bb[i];
            for (int k = 0; k < 10; k++) s += W[i * 10 + k] * dd[k];
            dn[i] = s;
        }
        __syncthreads();
        src ^= 1;
    }

    float* S  = src ? Sb : Sa;
    float* dd = src ? db : da;
    for (int i = t; i < 690; i += nt) S8out[i] = S[i];
    for (int i = t; i < 10; i += nt) {
        float s = dd[i];
        for (int k = 0; k < 69; k++) s += S[i * 69 + k] * b0[k];
        beff[i] = s;
    }
}

__global__ void prep_fold0(const float* __restrict__ W0,
                           const float* __restrict__ S8,
                           float* __restrict__ Wt)
{
    int idx = blockIdx.x * blockDim.x + threadIdx.x;  // o*784 + j
    if (idx >= 7840) return;
    int o = idx / 784, j = idx - o * 784;
    float s = 0.f;
    for (int k = 0; k < 69; k++) s += S8[o * 69 + k] * W0[k * 784 + j];
    Wt[j * 10 + o] = s;  // [784][10]
}

// ---- main: 4-wave row split, s_load weights, barrier-free K loop ----

#define LOADG(dst, g)                                               \
    _Pragma("unroll")                                               \
    for (int i = 0; i < 7; i++)                                     \
        dst[i] = *(const float4*)(xp + (g) * 28 + i * 4);

#define COMP(src, g)                                                \
    _Pragma("unroll")                                               \
    for (int i = 0; i < 7; i++) {                                   \
        const float* w = wp + ((g) * 28 + i * 4) * 10;              \
        _Pragma("unroll")                                           \
        for (int o = 0; o < 10; o++) acc[o] = fmaf(src[i].x, w[o],      acc[o]); \
        _Pragma("unroll")                                           \
        for (int o = 0; o < 10; o++) acc[o] = fmaf(src[i].y, w[10 + o], acc[o]); \
        _Pragma("unroll")                                           \
        for (int o = 0; o < 10; o++) acc[o] = fmaf(src[i].z, w[20 + o], acc[o]); \
        _Pragma("unroll")                                           \
        for (int o = 0; o < 10; o++) acc[o] = fmaf(src[i].w, w[30 + o], acc[o]); \
    }

__global__ __launch_bounds__(256, 4) void linear_main(
    const float* __restrict__ x, const float* __restrict__ Wt,
    const float* __restrict__ beff, float* __restrict__ out)
{
    __shared__ float part[3 * 64 * 10];
    const int t = threadIdx.x;
    const int lane = t & 63;
    // readfirstlane: force wave-id into SGPR so Wt addressing is provably
    // uniform -> compiler emits s_load for all weight reads (zero VMEM).
    const int q = __builtin_amdgcn_readfirstlane(t >> 6);
    const long row = (long)blockIdx.x * 64 + lane;

    const float* xp = x + row * 784 + q * 196;          // per-lane
    const float* __restrict__ wp = Wt + q * 1960;       // wave-uniform

    float acc[10];
#pragma unroll
    for (int o = 0; o < 10; o++) acc[o] = 0.f;

    float4 A[7], Bv[7];
    // 7 groups of 7 float4 (49 float4 = 196 floats per wave's j-range),
    // ping-pong prefetch: issue group g+1's loads before computing group g.
    LOADG(A, 0)
    LOADG(Bv, 1) COMP(A, 0)
    LOADG(A, 2)  COMP(Bv, 1)
    LOADG(Bv, 3) COMP(A, 2)
    LOADG(A, 4)  COMP(Bv, 3)
    LOADG(Bv, 5) COMP(A, 4)
    LOADG(A, 6)  COMP(Bv, 5)
    COMP(A, 6)

    // combine 4 wave-partials through LDS (one barrier total)
    if (q != 0) {
#pragma unroll
        for (int o = 0; o < 10; o++) part[(q - 1) * 640 + lane * 10 + o] = acc[o];
    }
    __syncthreads();
    if (q == 0) {
#pragma unroll
        for (int w = 0; w < 3; w++)
#pragma unroll
            for (int o = 0; o < 10; o++) acc[o] += part[w * 640 + lane * 10 + o];
        float* op = out + row * 10;
#pragma unroll
        for (int o = 0; o < 10; o += 2)
            *(float2*)(op + o) = make_float2(acc[o] + beff[o], acc[o + 1] + beff[o + 1]);
    }
}

extern "C" void kernel_launch(void* const* d_in, const int* in_sizes, int n_in,
                              void* d_out, int out_size, void* d_ws, size_t ws_size,
                              hipStream_t stream) {
    const float* x  = (const float*)d_in[0];
    const float* W0 = (const float*)d_in[1];
    const float* b0 = (const float*)d_in[2];
    const float* W1 = (const float*)d_in[3];
    const float* b1 = (const float*)d_in[4];
    const float* W2 = (const float*)d_in[5];
    const float* b2 = (const float*)d_in[6];
    const float* W3 = (const float*)d_in[7];
    const float* b3 = (const float*)d_in[8];
    const float* W4 = (const float*)d_in[9];
    const float* b4 = (const float*)d_in[10];
    const float* W5 = (const float*)d_in[11];
    const float* b5 = (const float*)d_in[12];
    const float* W6 = (const float*)d_in[13];
    const float* b6 = (const float*)d_in[14];
    const float* W7 = (const float*)d_in[15];
    const float* b7 = (const float*)d_in[16];
    const float* W8 = (const float*)d_in[17];
    const float* b8 = (const float*)d_in[18];

    float* ws   = (float*)d_ws;
    float* Wt   = ws;            // 7840 floats: [784][10]
    float* beff = ws + 7840;     // 10 floats
    float* S8   = ws + 7856;     // 690 floats

    float* out = (float*)d_out;
    const int B = in_sizes[0] / 784;  // 65536

    prep_collapse<<<1, 256, 0, stream>>>(W1, b1, W2, b2, W3, b3, W4, b4,
                                         W5, b5, W6, b6, W7, b7, W8, b8,
                                         b0, S8, beff);
    prep_fold0<<<31, 256, 0, stream>>>(W0, S8, Wt);
    linear_main<<<B / 64, 256, 0, stream>>>(x, Wt, beff, out);
}